// Round 1
// baseline (933.534 us; speedup 1.0000x reference)
//
#include <hip/hip_runtime.h>
#include <math.h>

#define SEGL 21
#define FRQ 24
#define NTH 512

// ---------------- LDS layout for token kernel (floats) ----------------
#define O_WQ    0
#define O_WK    576
#define O_WV    1152
#define O_BQ    1728
#define O_BK    1752
#define O_BV    1776
#define O_RELK  1800
#define O_RELV  1908
#define O_GA    2016
#define O_BA    2040
#define O_W1    2064
#define O_B1    4368
#define O_W2    4464
#define O_B2    6768
#define O_GF    6792
#define O_BF    6816
#define O_PE    6840
#define O_R1    7344              // x/q/k/v region (4*525=2100); later hid (21*97=2037)
#define O_X     (O_R1)
#define O_Q     (O_R1+525)
#define O_K     (O_R1+1050)
#define O_V     (O_R1+1575)
#define O_HID   (O_R1)
#define O_SC    (O_R1+2100)       // 882 scores; later ff (525)
#define O_FF    (O_SC)
#define O_ATT   (O_SC+882)        // 525
#define O_RED   (O_ATT+525)       // 42 used
#define SMEM_TOT (O_RED+64)       // 10915 floats = 43.7 KB

// ---------------- kernel 0: positional encoding table ----------------
__global__ void posenc_kernel(float* __restrict__ pe) {
    int i = threadIdx.x;
    if (i < SEGL * FRQ) {
        int s = i / FRQ, f = i % FRQ;
        double e = (double)(2 * (f / 2)) / 24.0;
        double ang = (double)s / pow(10000.0, e);
        float v = (f & 1) ? cosf((float)ang) : sinf((float)ang);
        pe[i] = 0.01f * v + 0.01f;   // folded *0.01 + 0.01
    }
}

// ---------------- kernel 1: fused per-token transformer ----------------
__global__ __launch_bounds__(NTH, 6) void token_kernel(
    const float* __restrict__ inp,
    const float* __restrict__ wq, const float* __restrict__ bq,
    const float* __restrict__ wk, const float* __restrict__ bk,
    const float* __restrict__ wv, const float* __restrict__ bv,
    const float* __restrict__ relk, const float* __restrict__ relv,
    const float* __restrict__ ga, const float* __restrict__ ba,
    const float* __restrict__ w1, const float* __restrict__ b1,
    const float* __restrict__ w2, const float* __restrict__ b2,
    const float* __restrict__ gf, const float* __restrict__ bf,
    const float* __restrict__ pe, float* __restrict__ ffout)
{
    __shared__ float sm[SMEM_TOT];
    const int tid = threadIdx.x;
    const int n = blockIdx.x;

    // ---- stage weights + input (input read before sync; pe added after) ----
    float xin = 0.f;
    if (tid < 504) xin = inp[(size_t)n * 504 + tid];

    for (int i = tid; i < 576; i += NTH) { sm[O_WQ+i]=wq[i]; sm[O_WK+i]=wk[i]; sm[O_WV+i]=wv[i]; }
    if (tid < 24) { sm[O_BQ+tid]=bq[tid]; sm[O_BK+tid]=bk[tid]; sm[O_BV+tid]=bv[tid];
                    sm[O_GA+tid]=ga[tid]; sm[O_BA+tid]=ba[tid]; sm[O_B2+tid]=b2[tid];
                    sm[O_GF+tid]=gf[tid]; sm[O_BF+tid]=bf[tid]; }
    if (tid >= 64 && tid < 64+108)  { sm[O_RELK+tid-64]=relk[tid-64]; sm[O_RELV+tid-64]=relv[tid-64]; }
    if (tid >= 192 && tid < 192+96) { sm[O_B1+tid-192]=b1[tid-192]; }
    for (int i = tid; i < 2304; i += NTH) { sm[O_W1+i]=w1[i]; sm[O_W2+i]=w2[i]; }
    if (tid < 504) sm[O_PE+tid] = pe[tid];
    __syncthreads();

    // x[s][f] = inp[n][f][s] + pe[s][f]     (tid = f*21+s)
    if (tid < 504) {
        int f = tid / 21, s = tid % 21;
        sm[O_X + s*25 + f] = xin + sm[O_PE + s*24 + f];
    }
    __syncthreads();

    // ---- q,k,v = relu(x @ W + b) ----
    if (tid < 504) {
        int s = tid / 24, f = tid % 24;
        float aq = sm[O_BQ+f], ak = sm[O_BK+f], av = sm[O_BV+f];
        #pragma unroll
        for (int j = 0; j < 24; ++j) {
            float x = sm[O_X + s*25 + j];
            aq = fmaf(x, sm[O_WQ + j*24 + f], aq);
            ak = fmaf(x, sm[O_WK + j*24 + f], ak);
            av = fmaf(x, sm[O_WV + j*24 + f], av);
        }
        sm[O_Q + s*25 + f] = fmaxf(aq, 0.f);
        sm[O_K + s*25 + f] = fmaxf(ak, 0.f);
        sm[O_V + s*25 + f] = fmaxf(av, 0.f);
    }
    __syncthreads();

    // ---- logits = (q·k + q·rel_k) / sqrt(12) ----
    const float rsc = 0.28867513459481287f;
    for (int e = tid; e < 882; e += NTH) {
        int h = e / 441, r = e % 441, qs = r / 21, ks = r % 21;
        int idx = ks - qs; idx = idx < -4 ? -4 : (idx > 4 ? 4 : idx); idx += 4;
        float acc = 0.f;
        #pragma unroll
        for (int d = 0; d < 12; ++d)
            acc = fmaf(sm[O_Q + qs*25 + h*12 + d],
                       sm[O_K + ks*25 + h*12 + d] + sm[O_RELK + idx*12 + d], acc);
        sm[O_SC + e] = acc * rsc;
    }
    __syncthreads();

    // ---- softmax over ks (one thread per (h,qs) row) ----
    if (tid < 42) {
        int base = O_SC + tid * 21;
        float m = sm[base];
        for (int k2 = 1; k2 < 21; ++k2) m = fmaxf(m, sm[base+k2]);
        float sum = 0.f;
        for (int k2 = 0; k2 < 21; ++k2) { float ev = __expf(sm[base+k2]-m); sm[base+k2]=ev; sum+=ev; }
        float inv = 1.f / sum;
        for (int k2 = 0; k2 < 21; ++k2) sm[base+k2] *= inv;
    }
    __syncthreads();

    // ---- o = w·(v + rel_v) ; residual ----
    if (tid < 504) {
        int s = tid / 24, f = tid % 24, h = f / 12, d = f % 12;
        float acc = 0.f;
        #pragma unroll
        for (int k2 = 0; k2 < 21; ++k2) {
            int idx = k2 - s; idx = idx < -4 ? -4 : (idx > 4 ? 4 : idx); idx += 4;
            acc = fmaf(sm[O_SC + (h*21+s)*21 + k2],
                       sm[O_V + k2*25 + f] + sm[O_RELV + idx*12 + d], acc);
        }
        sm[O_ATT + s*25 + f] = acc + sm[O_X + s*25 + f];
    }
    __syncthreads();

    // ---- LN(attn) ----
    if (tid < 21) {
        float s1 = 0.f, s2 = 0.f;
        for (int f = 0; f < 24; ++f) { float v = sm[O_ATT+tid*25+f]; s1 += v; s2 = fmaf(v,v,s2); }
        float m = s1 * (1.f/24.f);
        sm[O_RED+tid*2]   = m;
        sm[O_RED+tid*2+1] = rsqrtf(s2*(1.f/24.f) - m*m + 1e-3f);
    }
    __syncthreads();
    if (tid < 504) {
        int s = tid / 24, f = tid % 24;
        float v = sm[O_ATT + s*25 + f];
        sm[O_ATT + s*25 + f] = fmaf(sm[O_GA+f], (v - sm[O_RED+s*2]) * sm[O_RED+s*2+1], sm[O_BA+f]);
    }
    __syncthreads();

    // ---- ff hidden = relu(attn @ w1 + b1), 4 cols per thread ----
    if (tid < 504) {
        int s = tid / 24, g = (tid % 24) * 4;
        float a0=sm[O_B1+g], a1=sm[O_B1+g+1], a2=sm[O_B1+g+2], a3=sm[O_B1+g+3];
        #pragma unroll
        for (int j = 0; j < 24; ++j) {
            float av = sm[O_ATT + s*25 + j];
            const float* wr = &sm[O_W1 + j*96 + g];
            a0 = fmaf(av, wr[0], a0); a1 = fmaf(av, wr[1], a1);
            a2 = fmaf(av, wr[2], a2); a3 = fmaf(av, wr[3], a3);
        }
        float* hd = &sm[O_HID + s*97 + g];
        hd[0]=fmaxf(a0,0.f); hd[1]=fmaxf(a1,0.f); hd[2]=fmaxf(a2,0.f); hd[3]=fmaxf(a3,0.f);
    }
    __syncthreads();

    // ---- ff out = hidden @ w2 + b2 ; residual ----
    if (tid < 504) {
        int s = tid / 24, f = tid % 24;
        float acc = sm[O_B2+f];
        #pragma unroll 8
        for (int c = 0; c < 96; ++c)
            acc = fmaf(sm[O_HID + s*97 + c], sm[O_W2 + c*24 + f], acc);
        sm[O_FF + s*25 + f] = acc + sm[O_ATT + s*25 + f];
    }
    __syncthreads();

    // ---- LN(ff) ----
    if (tid < 21) {
        float s1 = 0.f, s2 = 0.f;
        for (int f = 0; f < 24; ++f) { float v = sm[O_FF+tid*25+f]; s1 += v; s2 = fmaf(v,v,s2); }
        float m = s1 * (1.f/24.f);
        sm[O_RED+tid*2]   = m;
        sm[O_RED+tid*2+1] = rsqrtf(s2*(1.f/24.f) - m*m + 1e-3f);
    }
    __syncthreads();
    if (tid < 504) {
        int s = tid / 24, f = tid % 24;
        float v = sm[O_FF + s*25 + f];
        sm[O_FF + s*25 + f] = fmaf(sm[O_GF+f], (v - sm[O_RED+s*2]) * sm[O_RED+s*2+1], sm[O_BF+f]);
    }
    __syncthreads();

    // ---- write transposed: ffout[n][f*21+s] = ff[s][f] ----
    if (tid < 504) {
        int f = tid / 21, s = tid % 21;
        ffout[(size_t)n * 504 + tid] = sm[O_FF + s*25 + f];
    }
}

// ---------------- kernel 2: [N,504]@[504,512] + bias + relu + LN(512) ----------------
__global__ __launch_bounds__(256, 3) void dense_ln_kernel(
    const float* __restrict__ A, const float* __restrict__ wd, const float* __restrict__ bd,
    const float* __restrict__ g, const float* __restrict__ b, float* __restrict__ out)
{
    __shared__ float At[24*36];     // transposed+padded A tile [kk][r]
    __shared__ float Bs[24*512];    // B tile [kk][c]
    const int tid = threadIdx.x;
    const int tx = tid & 63, ty = tid >> 6;
    const int row0 = blockIdx.x * 32;

    float acc[8][8];
    #pragma unroll
    for (int r = 0; r < 8; ++r)
        #pragma unroll
        for (int j = 0; j < 8; ++j) acc[r][j] = 0.f;

    for (int k0 = 0; k0 < 504; k0 += 24) {
        __syncthreads();
        for (int i = tid; i < 768; i += 256) {
            int r = i / 24, kk = i % 24;
            At[kk*36 + r] = A[(size_t)(row0 + r)*504 + k0 + kk];
        }
        const float4* Bg = reinterpret_cast<const float4*>(wd + k0*512);
        float4* Bs4 = reinterpret_cast<float4*>(Bs);
        #pragma unroll
        for (int v = 0; v < 12; ++v) Bs4[tid + v*256] = Bg[tid + v*256];
        __syncthreads();

        #pragma unroll 4
        for (int kk = 0; kk < 24; ++kk) {
            float4 a0 = *reinterpret_cast<const float4*>(&At[kk*36 + ty*8]);
            float4 a1 = *reinterpret_cast<const float4*>(&At[kk*36 + ty*8 + 4]);
            float a[8] = {a0.x, a0.y, a0.z, a0.w, a1.x, a1.y, a1.z, a1.w};
            float bv[8];
            #pragma unroll
            for (int j = 0; j < 8; ++j) bv[j] = Bs[kk*512 + tx + 64*j];
            #pragma unroll
            for (int r = 0; r < 8; ++r)
                #pragma unroll
                for (int j = 0; j < 8; ++j)
                    acc[r][j] = fmaf(a[r], bv[j], acc[r][j]);
        }
    }

    // ---- epilogue: bias + relu + LN over 512 (each wave owns whole rows) ----
    float bdv[8], gv[8], bbv[8];
    #pragma unroll
    for (int j = 0; j < 8; ++j) { int c = tx + 64*j; bdv[j]=bd[c]; gv[j]=g[c]; bbv[j]=b[c]; }
    const int rowb = row0 + ty*8;
    #pragma unroll
    for (int r = 0; r < 8; ++r) {
        float v[8]; float s1 = 0.f, s2 = 0.f;
        #pragma unroll
        for (int j = 0; j < 8; ++j) {
            float t = fmaxf(acc[r][j] + bdv[j], 0.f);
            v[j] = t; s1 += t; s2 = fmaf(t, t, s2);
        }
        #pragma unroll
        for (int off = 32; off > 0; off >>= 1) {
            s1 += __shfl_xor(s1, off);
            s2 += __shfl_xor(s2, off);
        }
        float m  = s1 * (1.f/512.f);
        float rs = rsqrtf(s2 * (1.f/512.f) - m*m + 1e-3f);
        float* orow = out + (size_t)(rowb + r) * 512;
        #pragma unroll
        for (int j = 0; j < 8; ++j)
            orow[tx + 64*j] = fmaf(gv[j], (v[j]-m)*rs, bbv[j]);
    }
}

extern "C" void kernel_launch(void* const* d_in, const int* in_sizes, int n_in,
                              void* d_out, int out_size, void* d_ws, size_t ws_size,
                              hipStream_t stream)
{
    const float* inp  = (const float*)d_in[0];
    const float* wq   = (const float*)d_in[1];
    const float* bq   = (const float*)d_in[2];
    const float* wk   = (const float*)d_in[3];
    const float* bk   = (const float*)d_in[4];
    const float* wv   = (const float*)d_in[5];
    const float* bv   = (const float*)d_in[6];
    const float* relk = (const float*)d_in[7];
    const float* relv = (const float*)d_in[8];
    const float* ga   = (const float*)d_in[9];
    const float* ba   = (const float*)d_in[10];
    const float* w1   = (const float*)d_in[11];
    const float* b1   = (const float*)d_in[12];
    const float* w2   = (const float*)d_in[13];
    const float* b2   = (const float*)d_in[14];
    const float* gf   = (const float*)d_in[15];
    const float* bf   = (const float*)d_in[16];
    const float* wd   = (const float*)d_in[17];
    const float* bd   = (const float*)d_in[18];
    const float* gо_  = (const float*)d_in[19];
    const float* bo_  = (const float*)d_in[20];

    float* ws = (float*)d_ws;
    float* pe = ws;             // 504 floats
    float* ff = ws + 512;       // N*504 floats
    const int N = in_sizes[0] / 504;   // 32768

    hipLaunchKernelGGL(posenc_kernel, dim3(1), dim3(NTH), 0, stream, pe);
    hipLaunchKernelGGL(token_kernel, dim3(N), dim3(NTH), 0, stream,
                       inp, wq, bq, wk, bk, wv, bv, relk, relv, ga, ba,
                       w1, b1, w2, b2, gf, bf, pe, ff);
    hipLaunchKernelGGL(dense_ln_kernel, dim3(N/32), dim3(256), 0, stream,
                       ff, wd, bd, gо_, bo_, (float*)d_out);
}